// Round 13
// baseline (4639.581 us; speedup 1.0000x reference)
//
#include <hip/hip_runtime.h>

typedef _Float16 f16x8 __attribute__((ext_vector_type(8)));
typedef float f32x4 __attribute__((ext_vector_type(4)));

#define VOCAB 128
#define EMB 512
#define HID 1024
#define BATCH 256
#define TSEQ 256
#define SLOT (BATCH * HID)

// ---- workspace byte offsets ----
#define CTR0_B 0                                  // 256 u32
#define CTRG_B 1024
#define CTR1_B 2048
#define H0_B   4096                               // 4 slots * SLOT * 2B
#define H1_B   (H0_B + 4 * SLOT * 2)
#define PRE1_B (H1_B + 4 * SLOT * 2)              // 4 slots * SLOT * 4B
#define PROJ_B (PRE1_B + 4 * SLOT * 4)            // 128*1024*4
#define WIMG_B (PROJ_B + VOCAB * HID * 4)         // 3*32*65536 f16

// LLC-coherent bypass loads for ring data (h0/h1/pre1) — no inv needed (r5-proven)
#define LOADX4(dst, p) asm volatile("global_load_dwordx4 %0, %1, off sc0 sc1" : "=v"(dst) : "v"(p))
#define LOADD(dst, p)  asm volatile("global_load_dword %0, %1, off sc0 sc1" : "=v"(dst) : "v"(p))
// write-through device-coherent vector store (lands at LLC, leaves no dirty L2)
#define STOREX4(p, v)  asm volatile("global_store_dwordx4 %0, %1, off sc0 sc1" :: "v"(p), "v"(v) : "memory")
#define WAITV(n) do { asm volatile("s_waitcnt vmcnt(" #n ")" ::: "memory"); \
                      __builtin_amdgcn_sched_barrier(0); } while (0)

__device__ __forceinline__ f32x4 mfma16(f16x8 a, f16x8 b, f32x4 c) {
    return __builtin_amdgcn_mfma_f32_16x16x32_f16(a, b, c, 0, 0, 0);
}

__device__ __forceinline__ void spin64(unsigned int* p) {
    while (__hip_atomic_load(p, __ATOMIC_RELAXED, __HIP_MEMORY_SCOPE_AGENT) < 64u)
        __builtin_amdgcn_s_sleep(1);
}

// ---- pack one 1024x1024 f32 weight matrix into the LDS image (hi+lo f16) ----
// per col-block cb: [kc 0..31][half][nf 0..1][g16 0..3][ar 0..15][8 f16]
__global__ __launch_bounds__(256) void pack_w(const float* __restrict__ W,
                                              _Float16* __restrict__ img) {
    int i = blockIdx.x * 256 + threadIdx.x;
    if (i >= HID * 128) return;
    const int n = i >> 7;
    const int c = i & 127;
    const int cb = n >> 5;
    const int col = n & 31;
    const int nf = col >> 4, ar = col & 15;
    const int kc = c >> 2, g = c & 3;
    const float* src = W + (size_t)n * HID + c * 8;
    float4 u0 = *(const float4*)src;
    float4 u1 = *(const float4*)(src + 4);
    float uf[8] = {u0.x, u0.y, u0.z, u0.w, u1.x, u1.y, u1.z, u1.w};
    f16x8 hi, lo;
    #pragma unroll
    for (int j = 0; j < 8; ++j) {
        _Float16 h = (_Float16)uf[j];
        hi[j] = h;
        lo[j] = (_Float16)(uf[j] - (float)h);
    }
    const size_t base = (size_t)cb * 65536 + (size_t)kc * 2048 +
                        (size_t)nf * 512 + (size_t)g * 128 + (size_t)ar * 8;
    *(f16x8*)(img + base)        = hi;
    *(f16x8*)(img + base + 1024) = lo;
}

// ---- PROJ[v][n] = emb[v,:] . Wih0[n,:] + b_ih0[n]  (f32 exact) ----
__global__ __launch_bounds__(256) void proj_k(const float* __restrict__ emb,
                                              const float* __restrict__ Wih0,
                                              const float* __restrict__ b_ih0,
                                              float* __restrict__ PROJ) {
    int o = blockIdx.x * 256 + threadIdx.x;
    if (o >= VOCAB * HID) return;
    const int v = o >> 10, n = o & (HID - 1);
    const float* er = emb + (size_t)v * EMB;
    const float* wr = Wih0 + (size_t)n * EMB;
    float acc = 0.f;
    #pragma unroll 4
    for (int k = 0; k < EMB; k += 4) {
        float4 e = *(const float4*)(er + k);
        float4 w = *(const float4*)(wr + k);
        acc += e.x * w.x + e.y * w.y + e.z * w.z + e.w * w.w;
    }
    PROJ[o] = acc + b_ih0[n];
}

// ---- persistent RNN: 192 blocks (3 roles x 2 row-groups x 32 col-blocks) ----
#define ISSUE4(B0, B1, KCB) do { \
    const _Float16* q0_ = pr0 + (KCB) * 32; \
    const _Float16* q1_ = pr1 + (KCB) * 32; \
    LOADX4(B0[0], q0_);      LOADX4(B0[1], q0_ + 32); \
    LOADX4(B0[2], q0_ + 64); LOADX4(B0[3], q0_ + 96); \
    LOADX4(B1[0], q1_);      LOADX4(B1[1], q1_ + 32); \
    LOADX4(B1[2], q1_ + 64); LOADX4(B1[3], q1_ + 96); \
} while (0)

#define KC1(KC, AV0, AV1) do { \
    const _Float16* sb_ = simg + (KC) * 2048 + lane * 8; \
    f16x8 bh0_ = *(const f16x8*)sb_; \
    f16x8 bh1_ = *(const f16x8*)(sb_ + 512); \
    f16x8 bl0_ = *(const f16x8*)(sb_ + 1024); \
    f16x8 bl1_ = *(const f16x8*)(sb_ + 1536); \
    a00 = mfma16(AV0, bh0_, a00); a01 = mfma16(AV0, bh1_, a01); \
    a10 = mfma16(AV1, bh0_, a10); a11 = mfma16(AV1, bh1_, a11); \
    a00 = mfma16(AV0, bl0_, a00); a01 = mfma16(AV0, bl1_, a01); \
    a10 = mfma16(AV1, bl0_, a10); a11 = mfma16(AV1, bl1_, a11); \
} while (0)

#define KC4(KB, CB0, CB1) do { \
    KC1((KB) + 0, CB0[0], CB1[0]); \
    KC1((KB) + 1, CB0[1], CB1[1]); \
    KC1((KB) + 2, CB0[2], CB1[2]); \
    KC1((KB) + 3, CB0[3], CB1[3]); \
} while (0)

__global__ __launch_bounds__(256, 1) void rnn_run(
    const int* __restrict__ tokens,
    const float* __restrict__ b_hh0, const float* __restrict__ b_ih1,
    const float* __restrict__ b_hh1, char* __restrict__ ws)
{
    __shared__ _Float16 simg[65536];                 // 128 KB weight slice
    __shared__ __align__(16) char stageb[4][4096];   // 16 KB per-wave output staging

    unsigned int* ctr0 = (unsigned int*)(ws + CTR0_B);
    unsigned int* ctrG = (unsigned int*)(ws + CTRG_B);
    unsigned int* ctr1 = (unsigned int*)(ws + CTR1_B);
    _Float16* h0 = (_Float16*)(ws + H0_B);
    _Float16* h1 = (_Float16*)(ws + H1_B);
    float* pre1 = (float*)(ws + PRE1_B);
    const float* PROJ = (const float*)(ws + PROJ_B);
    const _Float16* wimg = (const _Float16*)(ws + WIMG_B);

    const int tid = threadIdx.x, lane = tid & 63, wv = tid >> 6;
    const int blk = blockIdx.x;
    const int role = blk >> 6;
    const int sub = blk & 63;
    const int cb = sub & 31, rg = sub >> 5;
    const int n0 = cb * 32;

    // stage weight slice into LDS (read-only, written by prior kernel -> cached ok)
    {
        const _Float16* gi = wimg + (size_t)(role * 32 + cb) * 65536;
        for (int i = tid; i < 8192; i += 256)
            *(f16x8*)&simg[(size_t)i * 8] = *(const f16x8*)&gi[(size_t)i * 8];
    }
    __syncthreads();

    const int ar = lane & 15;
    const int g16 = lane >> 4;
    const int rbase = rg * 128 + wv * 32;
    const int er0 = rbase + g16 * 4;

    const float* bias = (role == 0) ? b_hh0 : (role == 1) ? b_ih1 : b_hh1;
    const float b0 = bias[n0 + ar];
    const float b1 = bias[n0 + 16 + ar];
    unsigned int* ctr_pub = (role == 0) ? ctr0 : (role == 1) ? ctrG : ctr1;

    for (int st = 0; st < TSEQ; ++st) {
        // ---- waits: relaxed atomic polls (coherent at LLC; no cache inv) ----
        if (tid == 0) {
            if (role == 0) {
                if (st)      spin64(ctr0 + st - 1);
                if (st >= 4) spin64(ctrG + st - 4);
            } else if (role == 1) {
                spin64(ctr0 + st);
                if (st >= 4) spin64(ctr1 + st - 4);
            } else {
                spin64(ctrG + st);
                if (st)      spin64(ctr1 + st - 1);
            }
        }
        __syncthreads();

        const _Float16* A = (role == 0) ? h0 + (size_t)((st + 3) & 3) * SLOT
                          : (role == 1) ? h0 + (size_t)(st & 3) * SLOT
                                        : h1 + (size_t)((st + 3) & 3) * SLOT;
        const _Float16* pr0 = A + (size_t)(rbase + ar) * HID + g16 * 8;
        const _Float16* pr1 = pr0 + 16 * HID;

        f32x4 a00 = {}, a01 = {}, a10 = {}, a11 = {};
        f16x8 ca0[4], ca1[4], cb0[4], cb1[4];

        __builtin_amdgcn_sched_barrier(0);
        ISSUE4(ca0, ca1, 0);
        #pragma unroll
        for (int k8 = 0; k8 < 4; ++k8) {
            const int kb = k8 * 8;
            ISSUE4(cb0, cb1, kb + 4);
            WAITV(8);
            KC4(kb, ca0, ca1);
            if (k8 < 3) {
                ISSUE4(ca0, ca1, kb + 8);
                WAITV(8);
            } else {
                WAITV(0);
            }
            KC4(kb + 4, cb0, cb1);
        }
        __builtin_amdgcn_sched_barrier(0);

        // ---- epilogue: stage tile in LDS, then vector write-through stores ----
        if (role == 0) {
            _Float16* sg = (_Float16*)stageb[wv];
            _Float16* O = h0 + (size_t)(st & 3) * SLOT;
            #pragma unroll
            for (int mf = 0; mf < 2; ++mf) {
                #pragma unroll
                for (int r = 0; r < 4; ++r) {
                    const int rr = er0 + mf * 16 + r;
                    const int trow = g16 * 4 + mf * 16 + r;
                    const int tok = tokens[rr * TSEQ + st];
                    const float* pr = PROJ + (size_t)tok * HID + n0;
                    const float v0 = (mf ? a10[r] : a00[r]) + pr[ar] + b0;
                    const float v1 = (mf ? a11[r] : a01[r]) + pr[16 + ar] + b1;
                    sg[trow * 32 + ar]      = (_Float16)tanhf(v0);
                    sg[trow * 32 + 16 + ar] = (_Float16)tanhf(v1);
                }
            }
            __syncthreads();
            #pragma unroll
            for (int j = 0; j < 2; ++j) {
                const int trow = j * 16 + (lane >> 2);
                f32x4 sv = *(const f32x4*)((const char*)sg + trow * 64 + (lane & 3) * 16);
                STOREX4(O + (size_t)(rbase + trow) * HID + n0 + (lane & 3) * 8, sv);
            }
        } else if (role == 1) {
            float* sg = (float*)stageb[wv];
            float* O = pre1 + (size_t)(st & 3) * SLOT;
            #pragma unroll
            for (int mf = 0; mf < 2; ++mf) {
                #pragma unroll
                for (int r = 0; r < 4; ++r) {
                    const int trow = g16 * 4 + mf * 16 + r;
                    sg[trow * 32 + ar]      = (mf ? a10[r] : a00[r]) + b0;
                    sg[trow * 32 + 16 + ar] = (mf ? a11[r] : a01[r]) + b1;
                }
            }
            __syncthreads();
            #pragma unroll
            for (int i = 0; i < 4; ++i) {
                const int trow = i * 8 + (lane >> 3);
                f32x4 sv = *(const f32x4*)((const char*)sg + trow * 128 + (lane & 7) * 16);
                STOREX4(O + (size_t)(rbase + trow) * HID + n0 + (lane & 7) * 4, sv);
            }
        } else {
            const float* P = pre1 + (size_t)(st & 3) * SLOT;
            float pv0[8], pv1[8];
            // bypass reads of pre1 (r5-proven pattern), isolated vmcnt region
            #pragma unroll
            for (int mf = 0; mf < 2; ++mf) {
                #pragma unroll
                for (int r = 0; r < 4; ++r) {
                    const int rr = er0 + mf * 16 + r;
                    LOADD(pv0[mf * 4 + r], P + (size_t)rr * HID + n0 + ar);
                    LOADD(pv1[mf * 4 + r], P + (size_t)rr * HID + n0 + 16 + ar);
                }
            }
            WAITV(0);
            _Float16* sg = (_Float16*)stageb[wv];
            _Float16* O = h1 + (size_t)(st & 3) * SLOT;
            #pragma unroll
            for (int mf = 0; mf < 2; ++mf) {
                #pragma unroll
                for (int r = 0; r < 4; ++r) {
                    const int trow = g16 * 4 + mf * 16 + r;
                    const float v0 = (mf ? a10[r] : a00[r]) + pv0[mf * 4 + r] + b0;
                    const float v1 = (mf ? a11[r] : a01[r]) + pv1[mf * 4 + r] + b1;
                    sg[trow * 32 + ar]      = (_Float16)tanhf(v0);
                    sg[trow * 32 + 16 + ar] = (_Float16)tanhf(v1);
                }
            }
            __syncthreads();
            #pragma unroll
            for (int j = 0; j < 2; ++j) {
                const int trow = j * 16 + (lane >> 2);
                f32x4 sv = *(const f32x4*)((const char*)sg + trow * 64 + (lane & 3) * 16);
                STOREX4(O + (size_t)(rbase + trow) * HID + n0 + (lane & 3) * 8, sv);
            }
        }

        // drain write-through stores, then publish via atomic RMW (r8-proven)
        asm volatile("s_waitcnt vmcnt(0)" ::: "memory");
        __syncthreads();
        if (tid == 0)
            __hip_atomic_fetch_add(ctr_pub + st, 1u, __ATOMIC_RELAXED,
                                   __HIP_MEMORY_SCOPE_AGENT);
    }
}

// ---- head: out[m][n] = h1[255][m,:] . Wout[n,:] + b_out[n] ----
__global__ __launch_bounds__(256) void head2(const _Float16* __restrict__ h1last,
                                             const float* __restrict__ Wout,
                                             const float* __restrict__ b_out,
                                             float* __restrict__ out) {
    const int idx = blockIdx.x * 256 + threadIdx.x;
    const int m = idx >> 7, n = idx & 127;
    const _Float16* hr = h1last + (size_t)m * HID;
    const float* wr = Wout + (size_t)n * HID;
    float acc = 0.f;
    #pragma unroll 4
    for (int k = 0; k < HID; k += 8) {
        f16x8 hv = *(const f16x8*)(hr + k);
        float4 w0 = *(const float4*)(wr + k);
        float4 w1 = *(const float4*)(wr + k + 4);
        acc += (float)hv[0] * w0.x + (float)hv[1] * w0.y +
               (float)hv[2] * w0.z + (float)hv[3] * w0.w +
               (float)hv[4] * w1.x + (float)hv[5] * w1.y +
               (float)hv[6] * w1.z + (float)hv[7] * w1.w;
    }
    out[idx] = acc + b_out[n];
}

extern "C" void kernel_launch(void* const* d_in, const int* in_sizes, int n_in,
                              void* d_out, int out_size, void* d_ws, size_t ws_size,
                              hipStream_t stream) {
    const int*   tokens = (const int*)  d_in[0];
    const float* emb    = (const float*)d_in[1];
    const float* W_ih0  = (const float*)d_in[2];
    const float* W_hh0  = (const float*)d_in[3];
    const float* b_ih0  = (const float*)d_in[4];
    const float* b_hh0  = (const float*)d_in[5];
    const float* W_ih1  = (const float*)d_in[6];
    const float* W_hh1  = (const float*)d_in[7];
    const float* b_ih1  = (const float*)d_in[8];
    const float* b_hh1  = (const float*)d_in[9];
    const float* W_out  = (const float*)d_in[10];
    const float* b_out  = (const float*)d_in[11];
    float* out = (float*)d_out;

    char* ws = (char*)d_ws;
    _Float16* wimg = (_Float16*)(ws + WIMG_B);
    float* PROJ = (float*)(ws + PROJ_B);

    // zero counters + the t=-1 ring slots (slot 3 of h0 and h1)
    (void)hipMemsetAsync(ws + CTR0_B, 0, 4096, stream);
    (void)hipMemsetAsync(ws + H0_B + (size_t)3 * SLOT * 2, 0, (size_t)SLOT * 2, stream);
    (void)hipMemsetAsync(ws + H1_B + (size_t)3 * SLOT * 2, 0, (size_t)SLOT * 2, stream);

    // pack weight images (role 0: Whh0, role 1: Wih1, role 2: Whh1)
    pack_w<<<512, 256, 0, stream>>>(W_hh0, wimg);
    pack_w<<<512, 256, 0, stream>>>(W_ih1, wimg + (size_t)32 * 65536);
    pack_w<<<512, 256, 0, stream>>>(W_hh1, wimg + (size_t)64 * 65536);
    // fused input projection table (exact f32)
    proj_k<<<512, 256, 0, stream>>>(emb, W_ih0, b_ih0, PROJ);

    // persistent pipelined RNN (192 blocks, 1/CU, relaxed-counter synced)
    rnn_run<<<192, 256, 0, stream>>>(tokens, b_hh0, b_ih1, b_hh1, ws);

    // head from h1[255] (ring slot 3)
    head2<<<128, 256, 0, stream>>>((const _Float16*)(ws + H1_B) + (size_t)3 * SLOT,
                                   W_out, b_out, out);
}

// Round 14
// 4335.002 us; speedup vs baseline: 1.0703x; 1.0703x over previous
//
#include <hip/hip_runtime.h>

typedef _Float16 f16x8 __attribute__((ext_vector_type(8)));
typedef float f32x4 __attribute__((ext_vector_type(4)));

#define VOCAB 128
#define EMB 512
#define HID 1024
#define BATCH 256
#define TSEQ 256
#define SLOT (BATCH * HID)

// ---- workspace byte offsets ----
#define CTR0_B 0                                  // [rg 0..1][st 0..255] u32
#define CTRG_B 2048
#define CTR1_B 4096
#define H0_B   8192                               // 4 slots * SLOT * 2B
#define H1_B   (H0_B + 4 * SLOT * 2)
#define PRE1_B (H1_B + 4 * SLOT * 2)              // 4 slots * SLOT * 4B
#define PROJ_B (PRE1_B + 4 * SLOT * 4)            // 128*1024*4
#define WIMG_B (PROJ_B + VOCAB * HID * 4)         // 3*32*65536 f16

// LLC-coherent bypass loads for ring data (h0/h1/pre1) — no inv needed (r5/r13-proven)
#define LOADX4(dst, p) asm volatile("global_load_dwordx4 %0, %1, off sc0 sc1" : "=v"(dst) : "v"(p))
#define LOADD(dst, p)  asm volatile("global_load_dword %0, %1, off sc0 sc1" : "=v"(dst) : "v"(p))
// write-through device-coherent vector store (lands at LLC, leaves no dirty L2)
#define STOREX4(p, v)  asm volatile("global_store_dwordx4 %0, %1, off sc0 sc1" :: "v"(p), "v"(v) : "memory")
#define WAITV(n) do { asm volatile("s_waitcnt vmcnt(" #n ")" ::: "memory"); \
                      __builtin_amdgcn_sched_barrier(0); } while (0)

__device__ __forceinline__ f32x4 mfma16(f16x8 a, f16x8 b, f32x4 c) {
    return __builtin_amdgcn_mfma_f32_16x16x32_f16(a, b, c, 0, 0, 0);
}

__device__ __forceinline__ void spin32(unsigned int* p) {
    while (__hip_atomic_load(p, __ATOMIC_RELAXED, __HIP_MEMORY_SCOPE_AGENT) < 32u)
        __builtin_amdgcn_s_sleep(1);
}

// ---- pack one 1024x1024 f32 weight matrix into the LDS image (hi+lo f16) ----
// per col-block cb: [kc 0..31][half][nf 0..1][g16 0..3][ar 0..15][8 f16]
__global__ __launch_bounds__(256) void pack_w(const float* __restrict__ W,
                                              _Float16* __restrict__ img) {
    int i = blockIdx.x * 256 + threadIdx.x;
    if (i >= HID * 128) return;
    const int n = i >> 7;
    const int c = i & 127;
    const int cb = n >> 5;
    const int col = n & 31;
    const int nf = col >> 4, ar = col & 15;
    const int kc = c >> 2, g = c & 3;
    const float* src = W + (size_t)n * HID + c * 8;
    float4 u0 = *(const float4*)src;
    float4 u1 = *(const float4*)(src + 4);
    float uf[8] = {u0.x, u0.y, u0.z, u0.w, u1.x, u1.y, u1.z, u1.w};
    f16x8 hi, lo;
    #pragma unroll
    for (int j = 0; j < 8; ++j) {
        _Float16 h = (_Float16)uf[j];
        hi[j] = h;
        lo[j] = (_Float16)(uf[j] - (float)h);
    }
    const size_t base = (size_t)cb * 65536 + (size_t)kc * 2048 +
                        (size_t)nf * 512 + (size_t)g * 128 + (size_t)ar * 8;
    *(f16x8*)(img + base)        = hi;
    *(f16x8*)(img + base + 1024) = lo;
}

// ---- PROJ[v][n] = emb[v,:] . Wih0[n,:] + b_ih0[n]  (f32 exact) ----
__global__ __launch_bounds__(256) void proj_k(const float* __restrict__ emb,
                                              const float* __restrict__ Wih0,
                                              const float* __restrict__ b_ih0,
                                              float* __restrict__ PROJ) {
    int o = blockIdx.x * 256 + threadIdx.x;
    if (o >= VOCAB * HID) return;
    const int v = o >> 10, n = o & (HID - 1);
    const float* er = emb + (size_t)v * EMB;
    const float* wr = Wih0 + (size_t)n * EMB;
    float acc = 0.f;
    #pragma unroll 4
    for (int k = 0; k < EMB; k += 4) {
        float4 e = *(const float4*)(er + k);
        float4 w = *(const float4*)(wr + k);
        acc += e.x * w.x + e.y * w.y + e.z * w.z + e.w * w.w;
    }
    PROJ[o] = acc + b_ih0[n];
}

// ---- persistent RNN: 192 blocks (3 roles x 2 row-groups x 32 col-blocks) ----
#define ISSUE4(B0, B1, KCB) do { \
    const _Float16* q0_ = pr0 + (KCB) * 32; \
    const _Float16* q1_ = pr1 + (KCB) * 32; \
    LOADX4(B0[0], q0_);      LOADX4(B0[1], q0_ + 32); \
    LOADX4(B0[2], q0_ + 64); LOADX4(B0[3], q0_ + 96); \
    LOADX4(B1[0], q1_);      LOADX4(B1[1], q1_ + 32); \
    LOADX4(B1[2], q1_ + 64); LOADX4(B1[3], q1_ + 96); \
} while (0)

#define KC1(KC, AV0, AV1) do { \
    const _Float16* sb_ = simg + (KC) * 2048 + lane * 8; \
    f16x8 bh0_ = *(const f16x8*)sb_; \
    f16x8 bh1_ = *(const f16x8*)(sb_ + 512); \
    f16x8 bl0_ = *(const f16x8*)(sb_ + 1024); \
    f16x8 bl1_ = *(const f16x8*)(sb_ + 1536); \
    a00 = mfma16(AV0, bh0_, a00); a01 = mfma16(AV0, bh1_, a01); \
    a10 = mfma16(AV1, bh0_, a10); a11 = mfma16(AV1, bh1_, a11); \
    a00 = mfma16(AV0, bl0_, a00); a01 = mfma16(AV0, bl1_, a01); \
    a10 = mfma16(AV1, bl0_, a10); a11 = mfma16(AV1, bl1_, a11); \
} while (0)

#define KC4(KB, CB0, CB1) do { \
    KC1((KB) + 0, CB0[0], CB1[0]); \
    KC1((KB) + 1, CB0[1], CB1[1]); \
    KC1((KB) + 2, CB0[2], CB1[2]); \
    KC1((KB) + 3, CB0[3], CB1[3]); \
} while (0)

__global__ __launch_bounds__(256, 1) void rnn_run(
    const int* __restrict__ tokens,
    const float* __restrict__ b_hh0, const float* __restrict__ b_ih1,
    const float* __restrict__ b_hh1, char* __restrict__ ws)
{
    __shared__ _Float16 simg[65536];                 // 128 KB weight slice
    __shared__ __align__(16) char stageb[4][4096];   // 16 KB per-wave output staging

    _Float16* h0 = (_Float16*)(ws + H0_B);
    _Float16* h1 = (_Float16*)(ws + H1_B);
    float* pre1 = (float*)(ws + PRE1_B);
    const float* PROJ = (const float*)(ws + PROJ_B);
    const _Float16* wimg = (const _Float16*)(ws + WIMG_B);

    const int tid = threadIdx.x, lane = tid & 63, wv = tid >> 6;
    const int blk = blockIdx.x;
    const int role = blk >> 6;
    const int sub = blk & 63;
    const int cb = sub & 31, rg = sub >> 5;
    const int n0 = cb * 32;

    // rg-local counters: 32 publishers / 32-target waits per line
    unsigned int* c0 = (unsigned int*)(ws + CTR0_B) + (rg << 8);
    unsigned int* cG = (unsigned int*)(ws + CTRG_B) + (rg << 8);
    unsigned int* c1 = (unsigned int*)(ws + CTR1_B) + (rg << 8);
    unsigned int* ctr_pub = (role == 0) ? c0 : (role == 1) ? cG : c1;

    // stage weight slice into LDS (read-only, written by prior kernel -> cached ok)
    {
        const _Float16* gi = wimg + (size_t)(role * 32 + cb) * 65536;
        for (int i = tid; i < 8192; i += 256)
            *(f16x8*)&simg[(size_t)i * 8] = *(const f16x8*)&gi[(size_t)i * 8];
    }
    __syncthreads();

    const int ar = lane & 15;
    const int g16 = lane >> 4;
    const int rbase = rg * 128 + wv * 32;
    const int er0 = rbase + g16 * 4;

    const float* bias = (role == 0) ? b_hh0 : (role == 1) ? b_ih1 : b_hh1;
    const float b0 = bias[n0 + ar];
    const float b1 = bias[n0 + 16 + ar];

    for (int st = 0; st < TSEQ; ++st) {
        // ---- RAW waits only (rg-local, relaxed polls; WAR deferred) ----
        if (tid == 0) {
            if (role == 0) {
                if (st) spin32(c0 + st - 1);
            } else if (role == 1) {
                spin32(c0 + st);
            } else {
                spin32(cG + st);
                if (st) spin32(c1 + st - 1);
            }
        }
        __syncthreads();

        const _Float16* A = (role == 0) ? h0 + (size_t)((st + 3) & 3) * SLOT
                          : (role == 1) ? h0 + (size_t)(st & 3) * SLOT
                                        : h1 + (size_t)((st + 3) & 3) * SLOT;
        const _Float16* pr0 = A + (size_t)(rbase + ar) * HID + g16 * 8;
        const _Float16* pr1 = pr0 + 16 * HID;

        f32x4 a00 = {}, a01 = {}, a10 = {}, a11 = {};
        f16x8 cA0[4], cA1[4], cB0[4], cB1[4], cC0[4], cC1[4], cD0[4], cD1[4];
        float pv0[8], pv1[8];

        __builtin_amdgcn_sched_barrier(0);
        // role 2: pre1 epilogue reads issued first; absorbed by the first WAITV
        if (role == 2) {
            const float* P = pre1 + (size_t)(st & 3) * SLOT;
            #pragma unroll
            for (int mf = 0; mf < 2; ++mf) {
                #pragma unroll
                for (int r = 0; r < 4; ++r) {
                    const int rr = er0 + mf * 16 + r;
                    LOADD(pv0[mf * 4 + r], P + (size_t)rr * HID + n0 + ar);
                    LOADD(pv1[mf * 4 + r], P + (size_t)rr * HID + n0 + 16 + ar);
                }
            }
        }
        // 32-deep rotation: 4 buffer pairs in flight
        ISSUE4(cA0, cA1, 0);
        ISSUE4(cB0, cB1, 4);
        ISSUE4(cC0, cC1, 8);
        ISSUE4(cD0, cD1, 12);
        WAITV(24); KC4(0,  cA0, cA1); ISSUE4(cA0, cA1, 16);
        WAITV(24); KC4(4,  cB0, cB1); ISSUE4(cB0, cB1, 20);
        WAITV(24); KC4(8,  cC0, cC1); ISSUE4(cC0, cC1, 24);
        WAITV(24); KC4(12, cD0, cD1); ISSUE4(cD0, cD1, 28);
        WAITV(24); KC4(16, cA0, cA1);
        WAITV(16); KC4(20, cB0, cB1);
        WAITV(8);  KC4(24, cC0, cC1);
        WAITV(0);  KC4(28, cD0, cD1);
        __builtin_amdgcn_sched_barrier(0);

        // ---- deferred WAR waits (slot free?) just before stores ----
        if (tid == 0) {
            if (role == 0) {
                if (st >= 4) spin32(cG + st - 4);
            } else if (role == 1) {
                if (st >= 4) spin32(c1 + st - 4);
            }
        }
        __syncthreads();

        // ---- epilogue: stage tile in LDS, then vector write-through stores ----
        if (role == 0) {
            _Float16* sg = (_Float16*)stageb[wv];
            _Float16* O = h0 + (size_t)(st & 3) * SLOT;
            #pragma unroll
            for (int mf = 0; mf < 2; ++mf) {
                #pragma unroll
                for (int r = 0; r < 4; ++r) {
                    const int rr = er0 + mf * 16 + r;
                    const int trow = g16 * 4 + mf * 16 + r;
                    const int tok = tokens[rr * TSEQ + st];
                    const float* pr = PROJ + (size_t)tok * HID + n0;
                    const float v0 = (mf ? a10[r] : a00[r]) + pr[ar] + b0;
                    const float v1 = (mf ? a11[r] : a01[r]) + pr[16 + ar] + b1;
                    sg[trow * 32 + ar]      = (_Float16)tanhf(v0);
                    sg[trow * 32 + 16 + ar] = (_Float16)tanhf(v1);
                }
            }
            __syncthreads();
            #pragma unroll
            for (int j = 0; j < 2; ++j) {
                const int trow = j * 16 + (lane >> 2);
                f32x4 sv = *(const f32x4*)((const char*)sg + trow * 64 + (lane & 3) * 16);
                STOREX4(O + (size_t)(rbase + trow) * HID + n0 + (lane & 3) * 8, sv);
            }
        } else if (role == 1) {
            float* sg = (float*)stageb[wv];
            float* O = pre1 + (size_t)(st & 3) * SLOT;
            #pragma unroll
            for (int mf = 0; mf < 2; ++mf) {
                #pragma unroll
                for (int r = 0; r < 4; ++r) {
                    const int trow = g16 * 4 + mf * 16 + r;
                    sg[trow * 32 + ar]      = (mf ? a10[r] : a00[r]) + b0;
                    sg[trow * 32 + 16 + ar] = (mf ? a11[r] : a01[r]) + b1;
                }
            }
            __syncthreads();
            #pragma unroll
            for (int i = 0; i < 4; ++i) {
                const int trow = i * 8 + (lane >> 3);
                f32x4 sv = *(const f32x4*)((const char*)sg + trow * 128 + (lane & 7) * 16);
                STOREX4(O + (size_t)(rbase + trow) * HID + n0 + (lane & 7) * 4, sv);
            }
        } else {
            _Float16* sg = (_Float16*)stageb[wv];
            _Float16* O = h1 + (size_t)(st & 3) * SLOT;
            #pragma unroll
            for (int mf = 0; mf < 2; ++mf) {
                #pragma unroll
                for (int r = 0; r < 4; ++r) {
                    const int trow = g16 * 4 + mf * 16 + r;
                    const float v0 = (mf ? a10[r] : a00[r]) + pv0[mf * 4 + r] + b0;
                    const float v1 = (mf ? a11[r] : a01[r]) + pv1[mf * 4 + r] + b1;
                    sg[trow * 32 + ar]      = (_Float16)tanhf(v0);
                    sg[trow * 32 + 16 + ar] = (_Float16)tanhf(v1);
                }
            }
            __syncthreads();
            #pragma unroll
            for (int j = 0; j < 2; ++j) {
                const int trow = j * 16 + (lane >> 2);
                f32x4 sv = *(const f32x4*)((const char*)sg + trow * 64 + (lane & 3) * 16);
                STOREX4(O + (size_t)(rbase + trow) * HID + n0 + (lane & 3) * 8, sv);
            }
        }

        // drain write-through stores, then publish via atomic RMW (proven)
        asm volatile("s_waitcnt vmcnt(0)" ::: "memory");
        __syncthreads();
        if (tid == 0)
            __hip_atomic_fetch_add(ctr_pub + st, 1u, __ATOMIC_RELAXED,
                                   __HIP_MEMORY_SCOPE_AGENT);
    }
}

// ---- head: out[m][n] = h1[255][m,:] . Wout[n,:] + b_out[n] ----
__global__ __launch_bounds__(256) void head2(const _Float16* __restrict__ h1last,
                                             const float* __restrict__ Wout,
                                             const float* __restrict__ b_out,
                                             float* __restrict__ out) {
    const int idx = blockIdx.x * 256 + threadIdx.x;
    const int m = idx >> 7, n = idx & 127;
    const _Float16* hr = h1last + (size_t)m * HID;
    const float* wr = Wout + (size_t)n * HID;
    float acc = 0.f;
    #pragma unroll 4
    for (int k = 0; k < HID; k += 8) {
        f16x8 hv = *(const f16x8*)(hr + k);
        float4 w0 = *(const float4*)(wr + k);
        float4 w1 = *(const float4*)(wr + k + 4);
        acc += (float)hv[0] * w0.x + (float)hv[1] * w0.y +
               (float)hv[2] * w0.z + (float)hv[3] * w0.w +
               (float)hv[4] * w1.x + (float)hv[5] * w1.y +
               (float)hv[6] * w1.z + (float)hv[7] * w1.w;
    }
    out[idx] = acc + b_out[n];
}

extern "C" void kernel_launch(void* const* d_in, const int* in_sizes, int n_in,
                              void* d_out, int out_size, void* d_ws, size_t ws_size,
                              hipStream_t stream) {
    const int*   tokens = (const int*)  d_in[0];
    const float* emb    = (const float*)d_in[1];
    const float* W_ih0  = (const float*)d_in[2];
    const float* W_hh0  = (const float*)d_in[3];
    const float* b_ih0  = (const float*)d_in[4];
    const float* b_hh0  = (const float*)d_in[5];
    const float* W_ih1  = (const float*)d_in[6];
    const float* W_hh1  = (const float*)d_in[7];
    const float* b_ih1  = (const float*)d_in[8];
    const float* b_hh1  = (const float*)d_in[9];
    const float* W_out  = (const float*)d_in[10];
    const float* b_out  = (const float*)d_in[11];
    float* out = (float*)d_out;

    char* ws = (char*)d_ws;
    _Float16* wimg = (_Float16*)(ws + WIMG_B);
    float* PROJ = (float*)(ws + PROJ_B);

    // zero counters (8 KB) + the t=-1 ring slots (slot 3 of h0 and h1)
    (void)hipMemsetAsync(ws + CTR0_B, 0, 8192, stream);
    (void)hipMemsetAsync(ws + H0_B + (size_t)3 * SLOT * 2, 0, (size_t)SLOT * 2, stream);
    (void)hipMemsetAsync(ws + H1_B + (size_t)3 * SLOT * 2, 0, (size_t)SLOT * 2, stream);

    // pack weight images (role 0: Whh0, role 1: Wih1, role 2: Whh1)
    pack_w<<<512, 256, 0, stream>>>(W_hh0, wimg);
    pack_w<<<512, 256, 0, stream>>>(W_ih1, wimg + (size_t)32 * 65536);
    pack_w<<<512, 256, 0, stream>>>(W_hh1, wimg + (size_t)64 * 65536);
    // fused input projection table (exact f32)
    proj_k<<<512, 256, 0, stream>>>(emb, W_ih0, b_ih0, PROJ);

    // persistent pipelined RNN (192 blocks, 1/CU, rg-local RMW-counter synced)
    rnn_run<<<192, 256, 0, stream>>>(tokens, b_hh0, b_ih1, b_hh1, ws);

    // head from h1[255] (ring slot 3)
    head2<<<128, 256, 0, stream>>>((const _Float16*)(ws + H1_B) + (size_t)3 * SLOT,
                                   W_out, b_out, out);
}

// Round 17
// 4263.801 us; speedup vs baseline: 1.0881x; 1.0167x over previous
//
#include <hip/hip_runtime.h>

typedef _Float16 f16x8 __attribute__((ext_vector_type(8)));
typedef float f32x4 __attribute__((ext_vector_type(4)));

#define VOCAB 128
#define EMB 512
#define HID 1024
#define BATCH 256
#define TSEQ 256
#define SLOT (BATCH * HID)

// ---- workspace byte offsets ----
#define CTR0_B 0                                  // [rg 0..1][st 0..255] u32
#define CTRG_B 2048
#define CTR1_B 4096
#define H0_B   8192                               // 4 slots * SLOT * 2B
#define H1_B   (H0_B + 4 * SLOT * 2)
#define PRE1_B (H1_B + 4 * SLOT * 2)              // 4 slots * SLOT * 4B
#define PROJ_B (PRE1_B + 4 * SLOT * 4)            // 128*1024*4
#define WIMG_B (PROJ_B + VOCAB * HID * 4)         // 3*32*65536 f16

// LLC-coherent bypass loads for ring data (h0/h1/pre1) — r5/r13/r14-proven
#define LOADX4(dst, p) asm volatile("global_load_dwordx4 %0, %1, off sc0 sc1" : "=v"(dst) : "v"(p))
#define LOADD(dst, p)  asm volatile("global_load_dword %0, %1, off sc0 sc1" : "=v"(dst) : "v"(p))
// write-through device-coherent vector store (lands at LLC, leaves no dirty L2)
#define STOREX4(p, v)  asm volatile("global_store_dwordx4 %0, %1, off sc0 sc1" :: "v"(p), "v"(v) : "memory")
#define WAITV(n) do { asm volatile("s_waitcnt vmcnt(" #n ")" ::: "memory"); \
                      __builtin_amdgcn_sched_barrier(0); } while (0)

__device__ __forceinline__ f32x4 mfma16(f16x8 a, f16x8 b, f32x4 c) {
    return __builtin_amdgcn_mfma_f32_16x16x32_f16(a, b, c, 0, 0, 0);
}

// busy poll (no s_sleep): keeps the CU issue-active so clocks stay up
__device__ __forceinline__ void spin32(unsigned int* p) {
    while (__hip_atomic_load(p, __ATOMIC_RELAXED, __HIP_MEMORY_SCOPE_AGENT) < 32u) {}
}

// ---- pack one 1024x1024 f32 weight matrix into the LDS image (hi+lo f16) ----
// per col-block cb: [kc 0..31][half][nf 0..1][g16 0..3][ar 0..15][8 f16]
__global__ __launch_bounds__(256) void pack_w(const float* __restrict__ W,
                                              _Float16* __restrict__ img) {
    int i = blockIdx.x * 256 + threadIdx.x;
    if (i >= HID * 128) return;
    const int n = i >> 7;
    const int c = i & 127;
    const int cb = n >> 5;
    const int col = n & 31;
    const int nf = col >> 4, ar = col & 15;
    const int kc = c >> 2, g = c & 3;
    const float* src = W + (size_t)n * HID + c * 8;
    float4 u0 = *(const float4*)src;
    float4 u1 = *(const float4*)(src + 4);
    float uf[8] = {u0.x, u0.y, u0.z, u0.w, u1.x, u1.y, u1.z, u1.w};
    f16x8 hi, lo;
    #pragma unroll
    for (int j = 0; j < 8; ++j) {
        _Float16 h = (_Float16)uf[j];
        hi[j] = h;
        lo[j] = (_Float16)(uf[j] - (float)h);
    }
    const size_t base = (size_t)cb * 65536 + (size_t)kc * 2048 +
                        (size_t)nf * 512 + (size_t)g * 128 + (size_t)ar * 8;
    *(f16x8*)(img + base)        = hi;
    *(f16x8*)(img + base + 1024) = lo;
}

// ---- PROJ[v][n] = emb[v,:] . Wih0[n,:] + b_ih0[n]  (f32 exact) ----
__global__ __launch_bounds__(256) void proj_k(const float* __restrict__ emb,
                                              const float* __restrict__ Wih0,
                                              const float* __restrict__ b_ih0,
                                              float* __restrict__ PROJ) {
    int o = blockIdx.x * 256 + threadIdx.x;
    if (o >= VOCAB * HID) return;
    const int v = o >> 10, n = o & (HID - 1);
    const float* er = emb + (size_t)v * EMB;
    const float* wr = Wih0 + (size_t)n * EMB;
    float acc = 0.f;
    #pragma unroll 4
    for (int k = 0; k < EMB; k += 4) {
        float4 e = *(const float4*)(er + k);
        float4 w = *(const float4*)(wr + k);
        acc += e.x * w.x + e.y * w.y + e.z * w.z + e.w * w.w;
    }
    PROJ[o] = acc + b_ih0[n];
}

// ---- persistent RNN: 192 blocks (3 roles x 2 row-groups x 32 col-blocks) ----
#define ISSUE4(B0, B1, KCB) do { \
    const _Float16* q0_ = pr0 + (KCB) * 32; \
    const _Float16* q1_ = pr1 + (KCB) * 32; \
    LOADX4(B0[0], q0_);      LOADX4(B0[1], q0_ + 32); \
    LOADX4(B0[2], q0_ + 64); LOADX4(B0[3], q0_ + 96); \
    LOADX4(B1[0], q1_);      LOADX4(B1[1], q1_ + 32); \
    LOADX4(B1[2], q1_ + 64); LOADX4(B1[3], q1_ + 96); \
} while (0)

#define KC1(KC, AV0, AV1) do { \
    const _Float16* sb_ = simg + (KC) * 2048 + lane * 8; \
    f16x8 bh0_ = *(const f16x8*)sb_; \
    f16x8 bh1_ = *(const f16x8*)(sb_ + 512); \
    f16x8 bl0_ = *(const f16x8*)(sb_ + 1024); \
    f16x8 bl1_ = *(const f16x8*)(sb_ + 1536); \
    a00 = mfma16(AV0, bh0_, a00); a01 = mfma16(AV0, bh1_, a01); \
    a10 = mfma16(AV1, bh0_, a10); a11 = mfma16(AV1, bh1_, a11); \
    a00 = mfma16(AV0, bl0_, a00); a01 = mfma16(AV0, bl1_, a01); \
    a10 = mfma16(AV1, bl0_, a10); a11 = mfma16(AV1, bl1_, a11); \
} while (0)

#define KC4(KB, CB0, CB1) do { \
    KC1((KB) + 0, CB0[0], CB1[0]); \
    KC1((KB) + 1, CB0[1], CB1[1]); \
    KC1((KB) + 2, CB0[2], CB1[2]); \
    KC1((KB) + 3, CB0[3], CB1[3]); \
} while (0)

__global__ __launch_bounds__(256, 1) void rnn_run(
    const int* __restrict__ tokens,
    const float* __restrict__ b_hh0, const float* __restrict__ b_ih1,
    const float* __restrict__ b_hh1, char* __restrict__ ws)
{
    __shared__ _Float16 simg[65536];                 // 128 KB weight slice
    __shared__ __align__(16) char stageb[4][4096];   // 16 KB per-wave output staging

    _Float16* h0 = (_Float16*)(ws + H0_B);
    _Float16* h1 = (_Float16*)(ws + H1_B);
    float* pre1 = (float*)(ws + PRE1_B);
    const float* PROJ = (const float*)(ws + PROJ_B);
    const _Float16* wimg = (const _Float16*)(ws + WIMG_B);

    const int tid = threadIdx.x, lane = tid & 63, wv = tid >> 6;
    const int blk = blockIdx.x;
    const int role = blk >> 6;
    const int sub = blk & 63;
    const int cb = sub & 31, rg = sub >> 5;
    const int n0 = cb * 32;

    // rg-local counters: 32 publishers / 32-target waits per line
    unsigned int* c0 = (unsigned int*)(ws + CTR0_B) + (rg << 8);
    unsigned int* cG = (unsigned int*)(ws + CTRG_B) + (rg << 8);
    unsigned int* c1 = (unsigned int*)(ws + CTR1_B) + (rg << 8);
    unsigned int* ctr_pub = (role == 0) ? c0 : (role == 1) ? cG : c1;

    // stage weight slice into LDS (read-only, written by prior kernel -> cached ok)
    {
        const _Float16* gi = wimg + (size_t)(role * 32 + cb) * 65536;
        for (int i = tid; i < 8192; i += 256)
            *(f16x8*)&simg[(size_t)i * 8] = *(const f16x8*)&gi[(size_t)i * 8];
    }
    __syncthreads();

    const int ar = lane & 15;
    const int g16 = lane >> 4;
    const int rbase = rg * 128 + wv * 32;
    const int er0 = rbase + g16 * 4;

    const float* bias = (role == 0) ? b_hh0 : (role == 1) ? b_ih1 : b_hh1;
    const float b0 = bias[n0 + ar];
    const float b1 = bias[n0 + 16 + ar];

    for (int st = 0; st < TSEQ; ++st) {
        // ---- RAW waits: PER-WAVE (lane 0 spins; no block barrier). Each
        //      wave gates its own loads; waves skew -> poll latency hides
        //      under other waves' compute, CU stays issue-active. ----
        if (lane == 0) {
            if (role == 0) {
                if (st) spin32(c0 + st - 1);
            } else if (role == 1) {
                spin32(c0 + st);
            } else {
                spin32(cG + st);
                if (st) spin32(c1 + st - 1);
            }
        }

        const _Float16* A = (role == 0) ? h0 + (size_t)((st + 3) & 3) * SLOT
                          : (role == 1) ? h0 + (size_t)(st & 3) * SLOT
                                        : h1 + (size_t)((st + 3) & 3) * SLOT;
        const _Float16* pr0 = A + (size_t)(rbase + ar) * HID + g16 * 8;
        const _Float16* pr1 = pr0 + 16 * HID;

        f32x4 a00 = {}, a01 = {}, a10 = {}, a11 = {};
        f16x8 cA0[4], cA1[4], cB0[4], cB1[4], cC0[4], cC1[4], cD0[4], cD1[4];
        float pv0[8], pv1[8];

        __builtin_amdgcn_sched_barrier(0);
        // role 2: pre1 epilogue reads issued first; absorbed by the first WAITV
        if (role == 2) {
            const float* P = pre1 + (size_t)(st & 3) * SLOT;
            #pragma unroll
            for (int mf = 0; mf < 2; ++mf) {
                #pragma unroll
                for (int r = 0; r < 4; ++r) {
                    const int rr = er0 + mf * 16 + r;
                    LOADD(pv0[mf * 4 + r], P + (size_t)rr * HID + n0 + ar);
                    LOADD(pv1[mf * 4 + r], P + (size_t)rr * HID + n0 + 16 + ar);
                }
            }
        }
        // 32-deep rotation: 4 buffer pairs in flight (r14-proven)
        ISSUE4(cA0, cA1, 0);
        ISSUE4(cB0, cB1, 4);
        ISSUE4(cC0, cC1, 8);
        ISSUE4(cD0, cD1, 12);
        WAITV(24); KC4(0,  cA0, cA1); ISSUE4(cA0, cA1, 16);
        WAITV(24); KC4(4,  cB0, cB1); ISSUE4(cB0, cB1, 20);
        WAITV(24); KC4(8,  cC0, cC1); ISSUE4(cC0, cC1, 24);
        WAITV(24); KC4(12, cD0, cD1); ISSUE4(cD0, cD1, 28);
        WAITV(24); KC4(16, cA0, cA1);
        WAITV(16); KC4(20, cB0, cB1);
        WAITV(8);  KC4(24, cC0, cC1);
        WAITV(0);  KC4(28, cD0, cD1);
        __builtin_amdgcn_sched_barrier(0);

        // ---- deferred WAR waits (slot free?) just before stores; per-wave ----
        if (lane == 0) {
            if (role == 0) {
                if (st >= 4) spin32(cG + st - 4);
            } else if (role == 1) {
                if (st >= 4) spin32(c1 + st - 4);
            }
        }

        // ---- epilogue: stage tile in LDS, then vector write-through stores ----
        if (role == 0) {
            _Float16* sg = (_Float16*)stageb[wv];
            _Float16* O = h0 + (size_t)(st & 3) * SLOT;
            #pragma unroll
            for (int mf = 0; mf < 2; ++mf) {
                #pragma unroll
                for (int r = 0; r < 4; ++r) {
                    const int rr = er0 + mf * 16 + r;
                    const int trow = g16 * 4 + mf * 16 + r;
                    const int tok = tokens[rr * TSEQ + st];
                    const float* pr = PROJ + (size_t)tok * HID + n0;
                    const float v0 = (mf ? a10[r] : a00[r]) + pr[ar] + b0;
                    const float v1 = (mf ? a11[r] : a01[r]) + pr[16 + ar] + b1;
                    sg[trow * 32 + ar]      = (_Float16)tanhf(v0);
                    sg[trow * 32 + 16 + ar] = (_Float16)tanhf(v1);
                }
            }
            __syncthreads();
            #pragma unroll
            for (int j = 0; j < 2; ++j) {
                const int trow = j * 16 + (lane >> 2);
                f32x4 sv = *(const f32x4*)((const char*)sg + trow * 64 + (lane & 3) * 16);
                STOREX4(O + (size_t)(rbase + trow) * HID + n0 + (lane & 3) * 8, sv);
            }
        } else if (role == 1) {
            float* sg = (float*)stageb[wv];
            float* O = pre1 + (size_t)(st & 3) * SLOT;
            #pragma unroll
            for (int mf = 0; mf < 2; ++mf) {
                #pragma unroll
                for (int r = 0; r < 4; ++r) {
                    const int trow = g16 * 4 + mf * 16 + r;
                    sg[trow * 32 + ar]      = (mf ? a10[r] : a00[r]) + b0;
                    sg[trow * 32 + 16 + ar] = (mf ? a11[r] : a01[r]) + b1;
                }
            }
            __syncthreads();
            #pragma unroll
            for (int i = 0; i < 4; ++i) {
                const int trow = i * 8 + (lane >> 3);
                f32x4 sv = *(const f32x4*)((const char*)sg + trow * 128 + (lane & 7) * 16);
                STOREX4(O + (size_t)(rbase + trow) * HID + n0 + (lane & 7) * 4, sv);
            }
        } else {
            _Float16* sg = (_Float16*)stageb[wv];
            _Float16* O = h1 + (size_t)(st & 3) * SLOT;
            #pragma unroll
            for (int mf = 0; mf < 2; ++mf) {
                #pragma unroll
                for (int r = 0; r < 4; ++r) {
                    const int trow = g16 * 4 + mf * 16 + r;
                    const float v0 = (mf ? a10[r] : a00[r]) + pv0[mf * 4 + r] + b0;
                    const float v1 = (mf ? a11[r] : a01[r]) + pv1[mf * 4 + r] + b1;
                    sg[trow * 32 + ar]      = (_Float16)tanhf(v0);
                    sg[trow * 32 + 16 + ar] = (_Float16)tanhf(v1);
                }
            }
            __syncthreads();
            #pragma unroll
            for (int j = 0; j < 2; ++j) {
                const int trow = j * 16 + (lane >> 2);
                f32x4 sv = *(const f32x4*)((const char*)sg + trow * 64 + (lane & 3) * 16);
                STOREX4(O + (size_t)(rbase + trow) * HID + n0 + (lane & 3) * 8, sv);
            }
        }

        // drain write-through stores, then publish via atomic RMW (proven 4/4)
        asm volatile("s_waitcnt vmcnt(0)" ::: "memory");
        __syncthreads();
        if (tid == 0)
            __hip_atomic_fetch_add(ctr_pub + st, 1u, __ATOMIC_RELAXED,
                                   __HIP_MEMORY_SCOPE_AGENT);
    }
}

// ---- head: out[m][n] = h1[255][m,:] . Wout[n,:] + b_out[n] ----
__global__ __launch_bounds__(256) void head2(const _Float16* __restrict__ h1last,
                                             const float* __restrict__ Wout,
                                             const float* __restrict__ b_out,
                                             float* __restrict__ out) {
    const int idx = blockIdx.x * 256 + threadIdx.x;
    const int m = idx >> 7, n = idx & 127;
    const _Float16* hr = h1last + (size_t)m * HID;
    const float* wr = Wout + (size_t)n * HID;
    float acc = 0.f;
    #pragma unroll 4
    for (int k = 0; k < HID; k += 8) {
        f16x8 hv = *(const f16x8*)(hr + k);
        float4 w0 = *(const float4*)(wr + k);
        float4 w1 = *(const float4*)(wr + k + 4);
        acc += (float)hv[0] * w0.x + (float)hv[1] * w0.y +
               (float)hv[2] * w0.z + (float)hv[3] * w0.w +
               (float)hv[4] * w1.x + (float)hv[5] * w1.y +
               (float)hv[6] * w1.z + (float)hv[7] * w1.w;
    }
    out[idx] = acc + b_out[n];
}

extern "C" void kernel_launch(void* const* d_in, const int* in_sizes, int n_in,
                              void* d_out, int out_size, void* d_ws, size_t ws_size,
                              hipStream_t stream) {
    const int*   tokens = (const int*)  d_in[0];
    const float* emb    = (const float*)d_in[1];
    const float* W_ih0  = (const float*)d_in[2];
    const float* W_hh0  = (const float*)d_in[3];
    const float* b_ih0  = (const float*)d_in[4];
    const float* b_hh0  = (const float*)d_in[5];
    const float* W_ih1  = (const float*)d_in[6];
    const float* W_hh1  = (const float*)d_in[7];
    const float* b_ih1  = (const float*)d_in[8];
    const float* b_hh1  = (const float*)d_in[9];
    const float* W_out  = (const float*)d_in[10];
    const float* b_out  = (const float*)d_in[11];
    float* out = (float*)d_out;

    char* ws = (char*)d_ws;
    _Float16* wimg = (_Float16*)(ws + WIMG_B);
    float* PROJ = (float*)(ws + PROJ_B);

    // zero counters (8 KB) + the t=-1 ring slots (slot 3 of h0 and h1)
    (void)hipMemsetAsync(ws + CTR0_B, 0, 8192, stream);
    (void)hipMemsetAsync(ws + H0_B + (size_t)3 * SLOT * 2, 0, (size_t)SLOT * 2, stream);
    (void)hipMemsetAsync(ws + H1_B + (size_t)3 * SLOT * 2, 0, (size_t)SLOT * 2, stream);

    // pack weight images (role 0: Whh0, role 1: Wih1, role 2: Whh1)
    pack_w<<<512, 256, 0, stream>>>(W_hh0, wimg);
    pack_w<<<512, 256, 0, stream>>>(W_ih1, wimg + (size_t)32 * 65536);
    pack_w<<<512, 256, 0, stream>>>(W_hh1, wimg + (size_t)64 * 65536);
    // fused input projection table (exact f32)
    proj_k<<<512, 256, 0, stream>>>(emb, W_ih0, b_ih0, PROJ);

    // persistent pipelined RNN (192 blocks, 1/CU, rg-local RMW-counter synced)
    rnn_run<<<192, 256, 0, stream>>>(tokens, b_hh0, b_ih1, b_hh1, ws);

    // head from h1[255] (ring slot 3)
    head2<<<128, 256, 0, stream>>>((const _Float16*)(ws + H1_B) + (size_t)3 * SLOT,
                                   W_out, b_out, out);
}